// Round 6
// baseline (402.650 us; speedup 1.0000x reference)
//
#include <hip/hip_runtime.h>
#include <hip/hip_bf16.h>
#include <math.h>

// Problem constants
#define DM   1024   // d_model
#define NH   16     // heads
#define DKH  64     // d_k per head
#define BB   4      // batch
#define SS   2048   // seq
#define MT   8192   // B*S rows

// 0.125 * log2(e): folds score scale AND exp->exp2 conversion into Q projection
#define QSCALE 0.18033688011112042f

typedef short bf16x8 __attribute__((ext_vector_type(8)));
typedef float f32x4  __attribute__((ext_vector_type(4)));
typedef float f32x16 __attribute__((ext_vector_type(16)));

__device__ __forceinline__ unsigned short f2bf(float f) {
  union { float f; unsigned u; } a; a.f = f;
  unsigned r = (a.u + 0x7fffu + ((a.u >> 16) & 1u)) >> 16;  // RNE
  return (unsigned short)r;
}

__device__ __forceinline__ void load_lds16(const void* g, void* l) {
  __builtin_amdgcn_global_load_lds(
      (const __attribute__((address_space(1))) void*)g,
      (__attribute__((address_space(3))) void*)l, 16, 0, 0);
}

// ---------------------------------------------------------------------------
// fp32 -> bf16 conversion for 3 activations + 4 weight matrices
// ---------------------------------------------------------------------------
__global__ void cvt_all(const float* __restrict__ q, const float* __restrict__ k,
                        const float* __restrict__ v, const float* __restrict__ wq,
                        const float* __restrict__ wk, const float* __restrict__ wv,
                        const float* __restrict__ wo,
                        unsigned short* __restrict__ xq, unsigned short* __restrict__ xk,
                        unsigned short* __restrict__ xv, unsigned short* __restrict__ uwq,
                        unsigned short* __restrict__ uwk, unsigned short* __restrict__ uwv,
                        unsigned short* __restrict__ uwo) {
  const long NQ = (long)MT * DM / 4;   // float4 count per activation
  const long NW = (long)DM * DM / 4;   // float4 count per weight
  const long total = 3 * NQ + 4 * NW;
  for (long i = (long)blockIdx.x * blockDim.x + threadIdx.x; i < total;
       i += (long)gridDim.x * blockDim.x) {
    const float* s; unsigned short* d; long o;
    if      (i <     NQ)          { s = q;  d = xq;  o = i; }
    else if (i < 2 * NQ)          { s = k;  d = xk;  o = i - NQ; }
    else if (i < 3 * NQ)          { s = v;  d = xv;  o = i - 2 * NQ; }
    else if (i < 3 * NQ + NW)     { s = wq; d = uwq; o = i - 3 * NQ; }
    else if (i < 3 * NQ + 2 * NW) { s = wk; d = uwk; o = i - 3 * NQ - NW; }
    else if (i < 3 * NQ + 3 * NW) { s = wv; d = uwv; o = i - 3 * NQ - 2 * NW; }
    else                          { s = wo; d = uwo; o = i - 3 * NQ - 3 * NW; }
    float4 f = ((const float4*)s)[o];
    ushort4 u;
    u.x = f2bf(f.x); u.y = f2bf(f.y); u.z = f2bf(f.z); u.w = f2bf(f.w);
    ((ushort4*)d)[o] = u;
  }
}

// ---------------------------------------------------------------------------
// GEMM, 2-phase double-buffered (T3-minimum), BM=256 BN=128 BK=64,
// 512 thr = 8 waves (4M x 2N), per-wave 64x64 out, 16x16x32 bf16 MFMA.
// LDS 96 KiB (A 2x32K + B 2x16K), XOR-swizzled (row&7)<<4 both sides
// (pre-swizzled global source for global_load_lds, swizzled ds_read).
// Fused QKV via blockIdx.z (X/W/Y contiguous, stride MT*DM / DM*DM / MT*DM).
// MODE 0: write bf16 head-split [B,NH,S,DKH]. MODE 1: write fp32 [8192][1024].
// Y = (X @ W^T + b) * oscale (oscale applied for z==0 only).
// ---------------------------------------------------------------------------
template <int MODE>
__global__ __launch_bounds__(512, 2)
void gemm2ph(const unsigned short* __restrict__ Xb, const unsigned short* __restrict__ Wb,
             const float* __restrict__ bz0, const float* __restrict__ bz1,
             const float* __restrict__ bz2, float oscale0, void* __restrict__ Yb) {
  __shared__ __align__(16) unsigned short Al[2][256 * 64];
  __shared__ __align__(16) unsigned short Bl[2][128 * 64];

  const int t = threadIdx.x, lane = t & 63, w = t >> 6;
  const int wm = w >> 1, wn = w & 1;          // 4 x 2 wave grid
  const int z = blockIdx.z;
  const unsigned short* X  = Xb + (size_t)z * MT * DM;
  const unsigned short* Wt = Wb + (size_t)z * DM * DM;
  const float* bias = (z == 0) ? bz0 : (z == 1 ? bz1 : bz2);
  const float osc = (z == 0) ? oscale0 : 1.0f;
  const int m0 = blockIdx.y * 256, n0 = blockIdx.x * 128;
  const int lr = lane & 15, lg = lane >> 4;

  f32x4 acc[4][4] = {};

  // Staging decode: chunk c covers LDS bytes [16c,16c+16); row = c>>3 (128B rows),
  // slot = c&7; global col pre-swizzled: (slot*16) ^ ((row&7)<<4).  A: 4 chunks
  // per thread (rows 0..255), B: first 2 chunks (rows 0..127).
  int srow[4], scol[4];
#pragma unroll
  for (int p = 0; p < 4; ++p) {
    const int c = t + 512 * p;
    srow[p] = c >> 3;
    scol[p] = (((c & 7) * 16) ^ ((srow[p] & 7) << 4)) >> 1;   // shorts
  }

#define GSTAGE(kt_, buf_)                                                     \
  {                                                                           \
    _Pragma("unroll")                                                         \
    for (int p = 0; p < 4; ++p)                                               \
      load_lds16(X + (size_t)(m0 + srow[p]) * DM + (kt_) * 64 + scol[p],      \
                 &Al[buf_][(t + 512 * p) * 8]);                               \
    _Pragma("unroll")                                                         \
    for (int p = 0; p < 2; ++p)                                               \
      load_lds16(Wt + (size_t)(n0 + srow[p]) * DM + (kt_) * 64 + scol[p],     \
                 &Bl[buf_][(t + 512 * p) * 8]);                               \
  }

  GSTAGE(0, 0);
  asm volatile("s_waitcnt vmcnt(0)" ::: "memory");
  __syncthreads();

  // Swizzled read offsets (bytes).  row&7 == lr&7 for all frags.
  const int rsw = (lr & 7) << 4;
  int aoff[4][2], boff[4][2];
#pragma unroll
  for (int f = 0; f < 4; ++f)
#pragma unroll
    for (int kk = 0; kk < 2; ++kk) {
      aoff[f][kk] = (wm * 64 + f * 16 + lr) * 128 + ((kk * 64 + lg * 16) ^ rsw);
      boff[f][kk] = (wn * 64 + f * 16 + lr) * 128 + ((kk * 64 + lg * 16) ^ rsw);
    }

  for (int kt = 0; kt < 16; ++kt) {
    const int buf = kt & 1;
    if (kt + 1 < 16) GSTAGE(kt + 1, buf ^ 1);

    const char* Ab = (const char*)&Al[buf][0];
    const char* Bb = (const char*)&Bl[buf][0];
#pragma unroll
    for (int kk = 0; kk < 2; ++kk) {
      bf16x8 af[4], bfv[4];
#pragma unroll
      for (int mf = 0; mf < 4; ++mf) af[mf] = *(const bf16x8*)(Ab + aoff[mf][kk]);
#pragma unroll
      for (int nf = 0; nf < 4; ++nf) bfv[nf] = *(const bf16x8*)(Bb + boff[nf][kk]);
#pragma unroll
      for (int mf = 0; mf < 4; ++mf)
#pragma unroll
        for (int nf = 0; nf < 4; ++nf)
          acc[mf][nf] = __builtin_amdgcn_mfma_f32_16x16x32_bf16(af[mf], bfv[nf], acc[mf][nf], 0, 0, 0);
    }

    asm volatile("s_waitcnt vmcnt(0)" ::: "memory");
    __syncthreads();
  }

  // Epilogue. D frag: col = lane&15, row = (lane>>4)*4 + j  [m89-verified]
#pragma unroll
  for (int mf = 0; mf < 4; ++mf)
#pragma unroll
    for (int nf = 0; nf < 4; ++nf) {
      const int col = n0 + wn * 64 + nf * 16 + lr;     // feature
      const float bcol = bias[col];
#pragma unroll
      for (int j = 0; j < 4; ++j) {
        const int row = m0 + wm * 64 + mf * 16 + lg * 4 + j;   // token
        const float val = (acc[mf][nf][j] + bcol) * osc;
        if (MODE == 0) {
          const int b = row >> 11, s = row & 2047, h = col >> 6, dk = col & 63;
          ((unsigned short*)Yb)[(size_t)z * MT * DM +
              (((size_t)(b * NH + h)) * SS + s) * DKH + dk] = f2bf(val);
        } else {
          ((float*)Yb)[(size_t)row * DM + col] = val;
        }
      }
    }
}

// ---------------------------------------------------------------------------
// VH [bh][s][dk] -> VT [bh][dk][s]  (64x64 tiles through LDS)
// ---------------------------------------------------------------------------
__global__ __launch_bounds__(256)
void transposeV(const unsigned short* __restrict__ VH, unsigned short* __restrict__ VTg) {
  __shared__ unsigned short T[64][66];
  const int t = threadIdx.x;
  const int bh = blockIdx.y, s0 = blockIdx.x * 64;
  const unsigned short* src = VH + ((size_t)bh * SS + s0) * DKH;
#pragma unroll
  for (int p = 0; p < 2; ++p) {
    const int c = p * 256 + t, row = c >> 3, c8 = (c & 7) * 8;
    bf16x8 v = *(const bf16x8*)(src + (size_t)row * DKH + c8);
#pragma unroll
    for (int e = 0; e < 8; ++e) T[row][c8 + e] = (unsigned short)v[e];
  }
  __syncthreads();
#pragma unroll
  for (int p = 0; p < 2; ++p) {
    const int c = p * 256 + t, dk = c >> 3, s8 = (c & 7) * 8;
    bf16x8 v;
#pragma unroll
    for (int e = 0; e < 8; ++e) v[e] = (short)T[s8 + e][dk];
    *(bf16x8*)(VTg + ((size_t)bh * DKH + dk) * SS + s0 + s8) = v;
  }
}

// ---------------------------------------------------------------------------
// Flash attention, swapped-QK^T 32x32 structure (T12/m214 port, D=64).
// grid (S/256, B*NH), 512 thr = 8 waves x 32 q-rows.  (unchanged from R5)
// ---------------------------------------------------------------------------
__global__ __launch_bounds__(512, 4)
void attn(const unsigned short* __restrict__ Qh, const unsigned short* __restrict__ Kh,
          const unsigned short* __restrict__ VTg, unsigned short* __restrict__ Ctx) {
  __shared__ __align__(16) unsigned short Kl[2][4096];   // [64 key][64 dk] swizzled
  __shared__ __align__(16) unsigned short Vl[2][4096];   // [64 dk][64 key] swizzled

  const int t = threadIdx.x, lane = t & 63, w = t >> 6;
  const int lr32 = lane & 31, hi = lane >> 5;
  const int bh = blockIdx.y;
  const int q0 = blockIdx.x * 256;
  const unsigned short* Qp = Qh + (size_t)bh * SS * DKH;
  const unsigned short* Kp = Kh + (size_t)bh * SS * DKH;
  const unsigned short* Vp = VTg + (size_t)bh * DKH * SS;   // [dk][s]

  const int qrow = q0 + w * 32 + lr32;
  bf16x8 qB[4];
#pragma unroll
  for (int ks = 0; ks < 4; ++ks)
    qB[ks] = *(const bf16x8*)(Qp + (size_t)qrow * DKH + 16 * ks + 8 * hi);

  f32x16 accO[2] = {};
  float m = -INFINITY, l = 0.f;

  const int srow = t >> 3;
  const int scol = (((t & 7) * 16) ^ ((srow & 7) << 4)) >> 1;   // shorts

#define STAGE(kt_, buf_)                                                      \
  {                                                                           \
    load_lds16(Kp + (size_t)((kt_) * 64 + srow) * DKH + scol,                 \
               &Kl[buf_][t * 8]);                                             \
    load_lds16(Vp + (size_t)srow * SS + (kt_) * 64 + scol,                    \
               &Vl[buf_][t * 8]);                                             \
  }

  STAGE(0, 0);
  asm volatile("s_waitcnt vmcnt(0)" ::: "memory");
  __syncthreads();

  const int rsw = (lr32 & 7) << 4;
  int obase[4];
#pragma unroll
  for (int j = 0; j < 4; ++j)
    obase[j] = lr32 * 128 + ((32 * j + 16 * hi) ^ rsw);

  for (int kt = 0; kt < 32; ++kt) {
    const int buf = kt & 1;
    if (kt + 1 < 32) STAGE(kt + 1, buf ^ 1);

    const char* Kbase = (const char*)&Kl[buf][0];
    const char* Vbase = (const char*)&Vl[buf][0];

#pragma unroll
    for (int kb = 0; kb < 2; ++kb) {
      // ---- QK^T (swapped): s[r] = S[key = 32*kb + rho(r,hi)][qrow] ----
      f32x16 s = {};
      __builtin_amdgcn_s_setprio(1);
#pragma unroll
      for (int ks = 0; ks < 4; ++ks) {
        bf16x8 ka = *(const bf16x8*)(Kbase + kb * 4096 + obase[ks]);
        s = __builtin_amdgcn_mfma_f32_32x32x16_bf16(ka, qB[ks], s, 0, 0, 0);
      }
      __builtin_amdgcn_s_setprio(0);

      // ---- row max: in-lane tree + cross-half combine (shfl_xor 32) ----
      float m0 = fmaxf(fmaxf(s[0], s[1]), fmaxf(s[2], s[3]));
      float m1 = fmaxf(fmaxf(s[4], s[5]), fmaxf(s[6], s[7]));
      float m2 = fmaxf(fmaxf(s[8], s[9]), fmaxf(s[10], s[11]));
      float m3 = fmaxf(fmaxf(s[12], s[13]), fmaxf(s[14], s[15]));
      float pmax = fmaxf(fmaxf(m0, m1), fmaxf(m2, m3));
      pmax = fmaxf(pmax, __shfl_xor(pmax, 32));

      // ---- defer-max (T13): rescale only when max grows past THR=8 ----
      if (!__all(pmax - m <= 8.0f)) {
        const float mnew = fmaxf(m, pmax);
        const float al = __builtin_amdgcn_exp2f(m - mnew);
        l *= al;
        const int abase = hi * 16;
#pragma unroll
        for (int r = 0; r < 16; ++r) {
          const int rho4 = ((r & 3) + 8 * (r >> 2)) * 4;
          const float ar = __int_as_float(
              __builtin_amdgcn_ds_bpermute(abase + rho4, __float_as_int(al)));
          accO[0][r] *= ar;
          accO[1][r] *= ar;
        }
        m = mnew;
      }

      // ---- P = exp2(s - m), row sum ----
#pragma unroll
      for (int r = 0; r < 16; ++r) s[r] = __builtin_amdgcn_exp2f(s[r] - m);
      float s0 = (s[0] + s[1]) + (s[2] + s[3]);
      float s1 = (s[4] + s[5]) + (s[6] + s[7]);
      float s2 = (s[8] + s[9]) + (s[10] + s[11]);
      float s3 = (s[12] + s[13]) + (s[14] + s[15]);
      float ps = (s0 + s1) + (s2 + s3);
      ps += __shfl_xor(ps, 32);
      l += ps;

      // ---- pack P to bf16 pair-words ----
      unsigned W[8];
#pragma unroll
      for (int g = 0; g < 4; ++g) {
        asm("v_cvt_pk_bf16_f32 %0, %1, %2" : "=v"(W[2 * g])     : "v"(s[4 * g]),     "v"(s[4 * g + 1]));
        asm("v_cvt_pk_bf16_f32 %0, %1, %2" : "=v"(W[2 * g + 1]) : "v"(s[4 * g + 2]), "v"(s[4 * g + 3]));
      }

      // ---- build PV A-frags (T12) and accumulate O += P @ V ----
#pragma unroll
      for (int cl = 0; cl < 2; ++cl) {
        auto r0 = __builtin_amdgcn_permlane32_swap(W[4 * cl],     W[4 * cl + 2], false, false);
        auto r1 = __builtin_amdgcn_permlane32_swap(W[4 * cl + 1], W[4 * cl + 3], false, false);
        union { unsigned u[4]; bf16x8 v; } pa;
        pa.u[0] = r0[0]; pa.u[1] = r1[0]; pa.u[2] = r0[1]; pa.u[3] = r1[1];
        __builtin_amdgcn_s_setprio(1);
#pragma unroll
        for (int dblk = 0; dblk < 2; ++dblk) {
          bf16x8 vb = *(const bf16x8*)(Vbase + dblk * 4096 + obase[2 * kb + cl]);
          accO[dblk] = __builtin_amdgcn_mfma_f32_32x32x16_bf16(pa.v, vb, accO[dblk], 0, 0, 0);
        }
        __builtin_amdgcn_s_setprio(0);
      }
    }

    asm volatile("s_waitcnt vmcnt(0)" ::: "memory");
    __syncthreads();
  }

  // ---- epilogue: O[qrow][dk] / l[qrow] ----
  const float inv = 1.f / l;
  const int b = bh >> 4, h = bh & 15;
  const int abase = hi * 16;
#pragma unroll
  for (int r = 0; r < 16; ++r) {
    const int rho = (r & 3) + 8 * (r >> 2) + 4 * hi;
    const float invr = __int_as_float(
        __builtin_amdgcn_ds_bpermute(abase + ((r & 3) + 8 * (r >> 2)) * 4, __float_as_int(inv)));
    const int token = b * SS + q0 + w * 32 + rho;
#pragma unroll
    for (int dblk = 0; dblk < 2; ++dblk)
      Ctx[(size_t)token * DM + h * DKH + 32 * dblk + lr32] = f2bf(accO[dblk][r] * invr);
  }
}

// ---------------------------------------------------------------------------
// Launch
// ---------------------------------------------------------------------------
extern "C" void kernel_launch(void* const* d_in, const int* in_sizes, int n_in,
                              void* d_out, int out_size, void* d_ws, size_t ws_size,
                              hipStream_t stream) {
  const float* q  = (const float*)d_in[0];
  const float* k  = (const float*)d_in[1];
  const float* v  = (const float*)d_in[2];
  const float* wq = (const float*)d_in[3];
  const float* bq = (const float*)d_in[4];
  const float* wk = (const float*)d_in[5];
  const float* bk = (const float*)d_in[6];
  const float* wv = (const float*)d_in[7];
  const float* bv = (const float*)d_in[8];
  const float* wo = (const float*)d_in[9];
  const float* bo = (const float*)d_in[10];

  // Workspace layout (120 MB). XQ/XK/XV, WQb/WKb/WVb, QH/KH/VH each contiguous
  // so the fused QKV GEMM indexes them by blockIdx.z.  VT aliases XQ.
  char* ws = (char*)d_ws;
  const size_t ACT = (size_t)MT * DM * 2;   // 16 MB
  const size_t WSZ = (size_t)DM * DM * 2;   //  2 MB
  unsigned short* XQ  = (unsigned short*)(ws);
  unsigned short* XK  = (unsigned short*)(ws + ACT);
  unsigned short* XV  = (unsigned short*)(ws + 2 * ACT);
  unsigned short* WQb = (unsigned short*)(ws + 3 * ACT);
  unsigned short* WKb = (unsigned short*)(ws + 3 * ACT + WSZ);
  unsigned short* WVb = (unsigned short*)(ws + 3 * ACT + 2 * WSZ);
  unsigned short* WOb = (unsigned short*)(ws + 3 * ACT + 3 * WSZ);
  unsigned short* QH  = (unsigned short*)(ws + 3 * ACT + 4 * WSZ);
  unsigned short* KH  = (unsigned short*)(ws + 4 * ACT + 4 * WSZ);
  unsigned short* VH  = (unsigned short*)(ws + 5 * ACT + 4 * WSZ);
  unsigned short* CTX = (unsigned short*)(ws + 6 * ACT + 4 * WSZ);
  unsigned short* VT  = XQ;   // reuse

  cvt_all<<<dim3(2048), dim3(256), 0, stream>>>(q, k, v, wq, wk, wv, wo,
                                                XQ, XK, XV, WQb, WKb, WVb, WOb);

  // Fused Q/K/V projections: grid (N/128, M/256, 3) = (8, 32, 3) = 768 blocks.
  gemm2ph<0><<<dim3(DM / 128, MT / 256, 3), 512, 0, stream>>>(
      XQ, WQb, bq, bk, bv, QSCALE, QH);

  transposeV<<<dim3(SS / 64, BB * NH), 256, 0, stream>>>(VH, VT);

  attn<<<dim3(SS / 256, BB * NH), 512, 0, stream>>>(QH, KH, VT, CTX);

  // Output projection: grid (8, 32, 1) = 256 blocks, fp32 out.
  gemm2ph<1><<<dim3(DM / 128, MT / 256, 1), 512, 0, stream>>>(
      CTX, WOb, bo, bo, bo, 1.0f, (float*)d_out);
}

// Round 7
// 376.947 us; speedup vs baseline: 1.0682x; 1.0682x over previous
//
#include <hip/hip_runtime.h>
#include <hip/hip_bf16.h>
#include <math.h>

// Problem constants
#define DM   1024   // d_model
#define NH   16     // heads
#define DKH  64     // d_k per head
#define BB   4      // batch
#define SS   2048   // seq
#define MT   8192   // B*S rows

// 0.125 * log2(e): folds score scale AND exp->exp2 conversion into Q projection
#define QSCALE 0.18033688011112042f

typedef short bf16x8 __attribute__((ext_vector_type(8)));
typedef float f32x4  __attribute__((ext_vector_type(4)));
typedef float f32x16 __attribute__((ext_vector_type(16)));

__device__ __forceinline__ unsigned short f2bf(float f) {
  union { float f; unsigned u; } a; a.f = f;
  unsigned r = (a.u + 0x7fffu + ((a.u >> 16) & 1u)) >> 16;  // RNE
  return (unsigned short)r;
}

__device__ __forceinline__ void load_lds16(const void* g, void* l) {
  __builtin_amdgcn_global_load_lds(
      (const __attribute__((address_space(1))) void*)g,
      (__attribute__((address_space(3))) void*)l, 16, 0, 0);
}

// ---------------------------------------------------------------------------
// fp32 -> bf16 conversion for 3 activations + 4 weight matrices
// ---------------------------------------------------------------------------
__global__ void cvt_all(const float* __restrict__ q, const float* __restrict__ k,
                        const float* __restrict__ v, const float* __restrict__ wq,
                        const float* __restrict__ wk, const float* __restrict__ wv,
                        const float* __restrict__ wo,
                        unsigned short* __restrict__ xq, unsigned short* __restrict__ xk,
                        unsigned short* __restrict__ xv, unsigned short* __restrict__ uwq,
                        unsigned short* __restrict__ uwk, unsigned short* __restrict__ uwv,
                        unsigned short* __restrict__ uwo) {
  const long NQ = (long)MT * DM / 4;   // float4 count per activation
  const long NW = (long)DM * DM / 4;   // float4 count per weight
  const long total = 3 * NQ + 4 * NW;
  for (long i = (long)blockIdx.x * blockDim.x + threadIdx.x; i < total;
       i += (long)gridDim.x * blockDim.x) {
    const float* s; unsigned short* d; long o;
    if      (i <     NQ)          { s = q;  d = xq;  o = i; }
    else if (i < 2 * NQ)          { s = k;  d = xk;  o = i - NQ; }
    else if (i < 3 * NQ)          { s = v;  d = xv;  o = i - 2 * NQ; }
    else if (i < 3 * NQ + NW)     { s = wq; d = uwq; o = i - 3 * NQ; }
    else if (i < 3 * NQ + 2 * NW) { s = wk; d = uwk; o = i - 3 * NQ - NW; }
    else if (i < 3 * NQ + 3 * NW) { s = wv; d = uwv; o = i - 3 * NQ - 2 * NW; }
    else                          { s = wo; d = uwo; o = i - 3 * NQ - 3 * NW; }
    float4 f = ((const float4*)s)[o];
    ushort4 u;
    u.x = f2bf(f.x); u.y = f2bf(f.y); u.z = f2bf(f.z); u.w = f2bf(f.w);
    ((ushort4*)d)[o] = u;
  }
}

// ---------------------------------------------------------------------------
// GEMM, 2-phase double-buffered, BM=BN=128 BK=64, 512 thr = 8 waves (4M x 2N),
// per-wave 32x64 out, 16x16x32 bf16 MFMA.  LDS 64 KiB -> 2 blocks/CU
// (16 waves/CU): co-resident block hides the per-step vmcnt drain (R6 lesson:
// 96KB/1-block variant stalled at MfmaUtil 17%).  XOR swizzle (row&7)<<4 on
// both sides (pre-swizzled global source for global_load_lds, swizzled
// ds_read) -- measured 0 bank conflicts.
// Fused QKV via blockIdx.z (X/W/Y contiguous, stride MT*DM / DM*DM / MT*DM).
// MODE 0: write bf16 head-split [B,NH,S,DKH]. MODE 1: write fp32 [8192][1024].
// Y = (X @ W^T + b) * oscale (oscale applied for z==0 only).
// ---------------------------------------------------------------------------
template <int MODE>
__global__ __launch_bounds__(512, 4)
void gemm128x2(const unsigned short* __restrict__ Xb, const unsigned short* __restrict__ Wb,
               const float* __restrict__ bz0, const float* __restrict__ bz1,
               const float* __restrict__ bz2, float oscale0, void* __restrict__ Yb) {
  __shared__ __align__(16) unsigned short Al[2][128 * 64];
  __shared__ __align__(16) unsigned short Bl[2][128 * 64];

  const int t = threadIdx.x, lane = t & 63, w = t >> 6;
  const int wm = w >> 1, wn = w & 1;          // 4M x 2N wave grid
  const int z = blockIdx.z;
  const unsigned short* X  = Xb + (size_t)z * MT * DM;
  const unsigned short* Wt = Wb + (size_t)z * DM * DM;
  const float* bias = (z == 0) ? bz0 : (z == 1 ? bz1 : bz2);
  const float osc = (z == 0) ? oscale0 : 1.0f;
  const int m0 = blockIdx.y * 128, n0 = blockIdx.x * 128;
  const int lr = lane & 15, lg = lane >> 4;

  f32x4 acc[2][4] = {};

  // Staging decode: chunk c covers LDS bytes [16c,16c+16); row = c>>3 (128B
  // rows), slot = c&7; global col pre-swizzled: (slot*16) ^ ((row&7)<<4).
  // 1024 chunks per 16KB tile, 512 threads -> 2 chunks each for A and B.
  const unsigned short* aSrc[2];
  const unsigned short* bSrc[2];
#pragma unroll
  for (int p = 0; p < 2; ++p) {
    const int c = t + 512 * p;
    const int srow = c >> 3;
    const int scol = (((c & 7) * 16) ^ ((srow & 7) << 4)) >> 1;   // shorts
    aSrc[p] = X  + (size_t)(m0 + srow) * DM + scol;
    bSrc[p] = Wt + (size_t)(n0 + srow) * DM + scol;
  }

#define GSTAGE(kt_, buf_)                                                     \
  {                                                                           \
    _Pragma("unroll")                                                         \
    for (int p = 0; p < 2; ++p)                                               \
      load_lds16(aSrc[p] + (kt_) * 64, &Al[buf_][(t + 512 * p) * 8]);         \
    _Pragma("unroll")                                                         \
    for (int p = 0; p < 2; ++p)                                               \
      load_lds16(bSrc[p] + (kt_) * 64, &Bl[buf_][(t + 512 * p) * 8]);         \
  }

  GSTAGE(0, 0);
  asm volatile("s_waitcnt vmcnt(0)" ::: "memory");
  __syncthreads();

  // Swizzled read offsets (bytes).  row&7 == lr&7 for all fragments.
  const int rsw = (lr & 7) << 4;
  int aoff[2][2], boff[4][2];
#pragma unroll
  for (int mf = 0; mf < 2; ++mf)
#pragma unroll
    for (int kk = 0; kk < 2; ++kk)
      aoff[mf][kk] = (wm * 32 + mf * 16 + lr) * 128 + ((kk * 64 + lg * 16) ^ rsw);
#pragma unroll
  for (int nf = 0; nf < 4; ++nf)
#pragma unroll
    for (int kk = 0; kk < 2; ++kk)
      boff[nf][kk] = (wn * 64 + nf * 16 + lr) * 128 + ((kk * 64 + lg * 16) ^ rsw);

  for (int kt = 0; kt < 16; ++kt) {
    const int buf = kt & 1;
    if (kt + 1 < 16) GSTAGE(kt + 1, buf ^ 1);

    const char* Ab = (const char*)&Al[buf][0];
    const char* Bb = (const char*)&Bl[buf][0];
#pragma unroll
    for (int kk = 0; kk < 2; ++kk) {
      bf16x8 af[2], bfv[4];
#pragma unroll
      for (int mf = 0; mf < 2; ++mf) af[mf] = *(const bf16x8*)(Ab + aoff[mf][kk]);
#pragma unroll
      for (int nf = 0; nf < 4; ++nf) bfv[nf] = *(const bf16x8*)(Bb + boff[nf][kk]);
#pragma unroll
      for (int mf = 0; mf < 2; ++mf)
#pragma unroll
        for (int nf = 0; nf < 4; ++nf)
          acc[mf][nf] = __builtin_amdgcn_mfma_f32_16x16x32_bf16(af[mf], bfv[nf], acc[mf][nf], 0, 0, 0);
    }

    asm volatile("s_waitcnt vmcnt(0)" ::: "memory");
    __syncthreads();
  }

  // Epilogue. D frag: col = lane&15, row = (lane>>4)*4 + j  [m89-verified]
#pragma unroll
  for (int mf = 0; mf < 2; ++mf)
#pragma unroll
    for (int nf = 0; nf < 4; ++nf) {
      const int col = n0 + wn * 64 + nf * 16 + lr;     // feature
      const float bcol = bias[col];
#pragma unroll
      for (int j = 0; j < 4; ++j) {
        const int row = m0 + wm * 32 + mf * 16 + lg * 4 + j;   // token
        const float val = (acc[mf][nf][j] + bcol) * osc;
        if (MODE == 0) {
          const int b = row >> 11, s = row & 2047, h = col >> 6, dk = col & 63;
          ((unsigned short*)Yb)[(size_t)z * MT * DM +
              (((size_t)(b * NH + h)) * SS + s) * DKH + dk] = f2bf(val);
        } else {
          ((float*)Yb)[(size_t)row * DM + col] = val;
        }
      }
    }
}

// ---------------------------------------------------------------------------
// VH [bh][s][dk] -> VT [bh][dk][s]  (64x64 tiles through LDS)
// ---------------------------------------------------------------------------
__global__ __launch_bounds__(256)
void transposeV(const unsigned short* __restrict__ VH, unsigned short* __restrict__ VTg) {
  __shared__ unsigned short T[64][66];
  const int t = threadIdx.x;
  const int bh = blockIdx.y, s0 = blockIdx.x * 64;
  const unsigned short* src = VH + ((size_t)bh * SS + s0) * DKH;
#pragma unroll
  for (int p = 0; p < 2; ++p) {
    const int c = p * 256 + t, row = c >> 3, c8 = (c & 7) * 8;
    bf16x8 v = *(const bf16x8*)(src + (size_t)row * DKH + c8);
#pragma unroll
    for (int e = 0; e < 8; ++e) T[row][c8 + e] = (unsigned short)v[e];
  }
  __syncthreads();
#pragma unroll
  for (int p = 0; p < 2; ++p) {
    const int c = p * 256 + t, dk = c >> 3, s8 = (c & 7) * 8;
    bf16x8 v;
#pragma unroll
    for (int e = 0; e < 8; ++e) v[e] = (short)T[s8 + e][dk];
    *(bf16x8*)(VTg + ((size_t)bh * DKH + dk) * SS + s0 + s8) = v;
  }
}

// ---------------------------------------------------------------------------
// Flash attention, swapped-QK^T 32x32 structure (T12/m214 port, D=64).
// grid (S/256, B*NH), 512 thr = 8 waves x 32 q-rows.  (unchanged from R5)
// ---------------------------------------------------------------------------
__global__ __launch_bounds__(512, 4)
void attn(const unsigned short* __restrict__ Qh, const unsigned short* __restrict__ Kh,
          const unsigned short* __restrict__ VTg, unsigned short* __restrict__ Ctx) {
  __shared__ __align__(16) unsigned short Kl[2][4096];   // [64 key][64 dk] swizzled
  __shared__ __align__(16) unsigned short Vl[2][4096];   // [64 dk][64 key] swizzled

  const int t = threadIdx.x, lane = t & 63, w = t >> 6;
  const int lr32 = lane & 31, hi = lane >> 5;
  const int bh = blockIdx.y;
  const int q0 = blockIdx.x * 256;
  const unsigned short* Qp = Qh + (size_t)bh * SS * DKH;
  const unsigned short* Kp = Kh + (size_t)bh * SS * DKH;
  const unsigned short* Vp = VTg + (size_t)bh * DKH * SS;   // [dk][s]

  const int qrow = q0 + w * 32 + lr32;
  bf16x8 qB[4];
#pragma unroll
  for (int ks = 0; ks < 4; ++ks)
    qB[ks] = *(const bf16x8*)(Qp + (size_t)qrow * DKH + 16 * ks + 8 * hi);

  f32x16 accO[2] = {};
  float m = -INFINITY, l = 0.f;

  const int srow = t >> 3;
  const int scol = (((t & 7) * 16) ^ ((srow & 7) << 4)) >> 1;   // shorts

#define STAGE(kt_, buf_)                                                      \
  {                                                                           \
    load_lds16(Kp + (size_t)((kt_) * 64 + srow) * DKH + scol,                 \
               &Kl[buf_][t * 8]);                                             \
    load_lds16(Vp + (size_t)srow * SS + (kt_) * 64 + scol,                    \
               &Vl[buf_][t * 8]);                                             \
  }

  STAGE(0, 0);
  asm volatile("s_waitcnt vmcnt(0)" ::: "memory");
  __syncthreads();

  const int rsw = (lr32 & 7) << 4;
  int obase[4];
#pragma unroll
  for (int j = 0; j < 4; ++j)
    obase[j] = lr32 * 128 + ((32 * j + 16 * hi) ^ rsw);

  for (int kt = 0; kt < 32; ++kt) {
    const int buf = kt & 1;
    if (kt + 1 < 32) STAGE(kt + 1, buf ^ 1);

    const char* Kbase = (const char*)&Kl[buf][0];
    const char* Vbase = (const char*)&Vl[buf][0];

#pragma unroll
    for (int kb = 0; kb < 2; ++kb) {
      // ---- QK^T (swapped): s[r] = S[key = 32*kb + rho(r,hi)][qrow] ----
      f32x16 s = {};
      __builtin_amdgcn_s_setprio(1);
#pragma unroll
      for (int ks = 0; ks < 4; ++ks) {
        bf16x8 ka = *(const bf16x8*)(Kbase + kb * 4096 + obase[ks]);
        s = __builtin_amdgcn_mfma_f32_32x32x16_bf16(ka, qB[ks], s, 0, 0, 0);
      }
      __builtin_amdgcn_s_setprio(0);

      // ---- row max: in-lane tree + cross-half combine (shfl_xor 32) ----
      float m0 = fmaxf(fmaxf(s[0], s[1]), fmaxf(s[2], s[3]));
      float m1 = fmaxf(fmaxf(s[4], s[5]), fmaxf(s[6], s[7]));
      float m2 = fmaxf(fmaxf(s[8], s[9]), fmaxf(s[10], s[11]));
      float m3 = fmaxf(fmaxf(s[12], s[13]), fmaxf(s[14], s[15]));
      float pmax = fmaxf(fmaxf(m0, m1), fmaxf(m2, m3));
      pmax = fmaxf(pmax, __shfl_xor(pmax, 32));

      // ---- defer-max (T13): rescale only when max grows past THR=8 ----
      if (!__all(pmax - m <= 8.0f)) {
        const float mnew = fmaxf(m, pmax);
        const float al = __builtin_amdgcn_exp2f(m - mnew);
        l *= al;
        const int abase = hi * 16;
#pragma unroll
        for (int r = 0; r < 16; ++r) {
          const int rho4 = ((r & 3) + 8 * (r >> 2)) * 4;
          const float ar = __int_as_float(
              __builtin_amdgcn_ds_bpermute(abase + rho4, __float_as_int(al)));
          accO[0][r] *= ar;
          accO[1][r] *= ar;
        }
        m = mnew;
      }

      // ---- P = exp2(s - m), row sum ----
#pragma unroll
      for (int r = 0; r < 16; ++r) s[r] = __builtin_amdgcn_exp2f(s[r] - m);
      float s0 = (s[0] + s[1]) + (s[2] + s[3]);
      float s1 = (s[4] + s[5]) + (s[6] + s[7]);
      float s2 = (s[8] + s[9]) + (s[10] + s[11]);
      float s3 = (s[12] + s[13]) + (s[14] + s[15]);
      float ps = (s0 + s1) + (s2 + s3);
      ps += __shfl_xor(ps, 32);
      l += ps;

      // ---- pack P to bf16 pair-words ----
      unsigned W[8];
#pragma unroll
      for (int g = 0; g < 4; ++g) {
        asm("v_cvt_pk_bf16_f32 %0, %1, %2" : "=v"(W[2 * g])     : "v"(s[4 * g]),     "v"(s[4 * g + 1]));
        asm("v_cvt_pk_bf16_f32 %0, %1, %2" : "=v"(W[2 * g + 1]) : "v"(s[4 * g + 2]), "v"(s[4 * g + 3]));
      }

      // ---- build PV A-frags (T12) and accumulate O += P @ V ----
#pragma unroll
      for (int cl = 0; cl < 2; ++cl) {
        auto r0 = __builtin_amdgcn_permlane32_swap(W[4 * cl],     W[4 * cl + 2], false, false);
        auto r1 = __builtin_amdgcn_permlane32_swap(W[4 * cl + 1], W[4 * cl + 3], false, false);
        union { unsigned u[4]; bf16x8 v; } pa;
        pa.u[0] = r0[0]; pa.u[1] = r1[0]; pa.u[2] = r0[1]; pa.u[3] = r1[1];
        __builtin_amdgcn_s_setprio(1);
#pragma unroll
        for (int dblk = 0; dblk < 2; ++dblk) {
          bf16x8 vb = *(const bf16x8*)(Vbase + dblk * 4096 + obase[2 * kb + cl]);
          accO[dblk] = __builtin_amdgcn_mfma_f32_32x32x16_bf16(pa.v, vb, accO[dblk], 0, 0, 0);
        }
        __builtin_amdgcn_s_setprio(0);
      }
    }

    asm volatile("s_waitcnt vmcnt(0)" ::: "memory");
    __syncthreads();
  }

  // ---- epilogue: O[qrow][dk] / l[qrow] ----
  const float inv = 1.f / l;
  const int b = bh >> 4, h = bh & 15;
  const int abase = hi * 16;
#pragma unroll
  for (int r = 0; r < 16; ++r) {
    const int rho = (r & 3) + 8 * (r >> 2) + 4 * hi;
    const float invr = __int_as_float(
        __builtin_amdgcn_ds_bpermute(abase + ((r & 3) + 8 * (r >> 2)) * 4, __float_as_int(inv)));
    const int token = b * SS + q0 + w * 32 + rho;
#pragma unroll
    for (int dblk = 0; dblk < 2; ++dblk)
      Ctx[(size_t)token * DM + h * DKH + 32 * dblk + lr32] = f2bf(accO[dblk][r] * invr);
  }
}

// ---------------------------------------------------------------------------
// Launch
// ---------------------------------------------------------------------------
extern "C" void kernel_launch(void* const* d_in, const int* in_sizes, int n_in,
                              void* d_out, int out_size, void* d_ws, size_t ws_size,
                              hipStream_t stream) {
  const float* q  = (const float*)d_in[0];
  const float* k  = (const float*)d_in[1];
  const float* v  = (const float*)d_in[2];
  const float* wq = (const float*)d_in[3];
  const float* bq = (const float*)d_in[4];
  const float* wk = (const float*)d_in[5];
  const float* bk = (const float*)d_in[6];
  const float* wv = (const float*)d_in[7];
  const float* bv = (const float*)d_in[8];
  const float* wo = (const float*)d_in[9];
  const float* bo = (const float*)d_in[10];

  // Workspace layout (120 MB). XQ/XK/XV, WQb/WKb/WVb, QH/KH/VH each contiguous
  // so the fused QKV GEMM indexes them by blockIdx.z.  VT aliases XQ.
  char* ws = (char*)d_ws;
  const size_t ACT = (size_t)MT * DM * 2;   // 16 MB
  const size_t WSZ = (size_t)DM * DM * 2;   //  2 MB
  unsigned short* XQ  = (unsigned short*)(ws);
  unsigned short* XK  = (unsigned short*)(ws + ACT);
  unsigned short* XV  = (unsigned short*)(ws + 2 * ACT);
  unsigned short* WQb = (unsigned short*)(ws + 3 * ACT);
  unsigned short* WKb = (unsigned short*)(ws + 3 * ACT + WSZ);
  unsigned short* WVb = (unsigned short*)(ws + 3 * ACT + 2 * WSZ);
  unsigned short* WOb = (unsigned short*)(ws + 3 * ACT + 3 * WSZ);
  unsigned short* QH  = (unsigned short*)(ws + 3 * ACT + 4 * WSZ);
  unsigned short* KH  = (unsigned short*)(ws + 4 * ACT + 4 * WSZ);
  unsigned short* VH  = (unsigned short*)(ws + 5 * ACT + 4 * WSZ);
  unsigned short* CTX = (unsigned short*)(ws + 6 * ACT + 4 * WSZ);
  unsigned short* VT  = XQ;   // reuse

  cvt_all<<<dim3(2048), dim3(256), 0, stream>>>(q, k, v, wq, wk, wv, wo,
                                                XQ, XK, XV, WQb, WKb, WVb, WOb);

  // Fused Q/K/V projections: grid (8, 64, 3) = 1536 blocks = 3 exact
  // block-waves at 2 blocks/CU.
  gemm128x2<0><<<dim3(DM / 128, MT / 128, 3), 512, 0, stream>>>(
      XQ, WQb, bq, bk, bv, QSCALE, QH);

  transposeV<<<dim3(SS / 64, BB * NH), 256, 0, stream>>>(VH, VT);

  attn<<<dim3(SS / 256, BB * NH), 512, 0, stream>>>(QH, KH, VT, CTX);

  // Output projection: grid (8, 64, 1) = 512 blocks = 1 exact block-wave.
  gemm128x2<1><<<dim3(DM / 128, MT / 128, 1), 512, 0, stream>>>(
      CTX, WOb, bo, bo, bo, 1.0f, (float*)d_out);
}